// Round 8
// baseline (1070.140 us; speedup 1.0000x reference)
//
#include <hip/hip_runtime.h>
#include <hip/hip_bf16.h>

#define EPSF 1e-20f

typedef __hip_bfloat16 bf16;

__device__ __forceinline__ float b2f(bf16 v) { return __bfloat162float(v); }
__device__ __forceinline__ bf16 f2b(float v) { return __float2bfloat16(v); }

// ---- problem dims (fixed by setup_inputs) ----
#define B_ 16
#define H1 352
#define W1 1216
#define H2 176
#define W2 608
#define H3 88
#define W3 304
#define H4 44
#define W4 152

// ---------------------------------------------------------------------------
// Weight prep (f32 inputs): w = softplus(10*p)/10, plus per-out-ch kernel sums.
// wb layout (floats): wt1@0(50) s1@64(2) | wt2@96(100) s2@224(2) |
// wt3@256(100) s3@384(2) | wt4@416(72) s4@512(2) | wt5@544(72) s5@640(2) |
// wt6@672(72) s6@768(2) | wt7@800(2) s7@804(1).
// ---------------------------------------------------------------------------
__global__ void prep_weights(const float* w1, const float* w2, const float* w3,
                             const float* w4, const float* w5, const float* w6,
                             const float* w7, float* wb) {
    const float* ptrs[7] = {w1, w2, w3, w4, w5, w6, w7};
    const int ns[7]   = {50, 100, 100, 72, 72, 72, 2};
    const int offs[7] = {0, 96, 256, 416, 544, 672, 800};
    for (int it = 0; it < 7; ++it)
        for (int i = threadIdx.x; i < ns[it]; i += blockDim.x) {
            float z = 10.f * ptrs[it][i];
            float sp = (z > 20.f) ? z : log1pf(expf(z));
            wb[offs[it] + i] = sp * 0.1f;
        }
    __syncthreads();
    if (threadIdx.x == 0) {
        const int souts[7] = {2, 2, 2, 2, 2, 2, 1};
        const int klen[7]  = {25, 50, 50, 36, 36, 36, 2};
        const int soff[7]  = {64, 224, 384, 512, 640, 768, 804};
        for (int it = 0; it < 7; ++it)
            for (int o = 0; o < souts[it]; ++o) {
                float s = 0.f;
                for (int i = 0; i < klen[it]; ++i) s += wb[offs[it] + o * klen[it] + i];
                wb[soff[it] + o] = s;
            }
    }
}

// ---------------------------------------------------------------------------
// Layer 1 conv: 5x5 pad2 nconv, 1 in ch (f32) -> 2 out ch (bf16).
// ---------------------------------------------------------------------------
__global__ void nconv5_c1f(const float* __restrict__ xin, const float* __restrict__ cin,
                           const float* __restrict__ wt, const float* __restrict__ sb,
                           const float* __restrict__ bias,
                           bf16* __restrict__ xout, bf16* __restrict__ cout) {
    __shared__ float sw[54];
    for (int i = threadIdx.x; i < 50; i += blockDim.x) sw[i] = wt[i];
    if (threadIdx.x < 2) {
        sw[50 + threadIdx.x] = sb[threadIdx.x];
        sw[52 + threadIdx.x] = bias[threadIdx.x];
    }
    __syncthreads();
    int idx = blockIdx.x * blockDim.x + threadIdx.x;
    const int total = B_ * H1 * W1;
    if (idx >= total) return;
    int w = idx % W1; int t = idx / W1; int h = t % H1; int b = t / H1;
    const float* xp = xin + (long)b * (H1 * W1);
    const float* cp = cin + (long)b * (H1 * W1);
    float nom0 = 0, den0 = 0, nom1 = 0, den1 = 0;
    #pragma unroll
    for (int dh = 0; dh < 5; ++dh) {
        int ih = h + dh - 2;
        if (ih < 0 || ih >= H1) continue;
        #pragma unroll
        for (int dw = 0; dw < 5; ++dw) {
            int iw = w + dw - 2;
            if (iw < 0 || iw >= W1) continue;
            float c = cp[ih * W1 + iw];
            float p = xp[ih * W1 + iw] * c;
            float w0 = sw[dh * 5 + dw];
            float w1 = sw[25 + dh * 5 + dw];
            nom0 = fmaf(w0, p, nom0); den0 = fmaf(w0, c, den0);
            nom1 = fmaf(w1, p, nom1); den1 = fmaf(w1, c, den1);
        }
    }
    long o0 = (long)(b * 2) * (H1 * W1) + h * W1 + w;
    long o1 = o0 + H1 * W1;
    xout[o0] = f2b(nom0 / (den0 + EPSF) + sw[52]);
    xout[o1] = f2b(nom1 / (den1 + EPSF) + sw[53]);
    cout[o0] = f2b(den0 / sw[50]);
    cout[o1] = f2b(den1 / sw[51]);
}

// ---------------------------------------------------------------------------
// 5x5 pad2 nconv, 2 in ch -> 2 out ch, bf16 I/O, fp32 accumulation.
// ---------------------------------------------------------------------------
__global__ void nconv5_c2(const bf16* __restrict__ xin, const bf16* __restrict__ cin,
                          const float* __restrict__ wt, const float* __restrict__ sb,
                          const float* __restrict__ bias,
                          bf16* __restrict__ xout, bf16* __restrict__ cout,
                          int H, int W) {
    __shared__ float sw[104];
    for (int i = threadIdx.x; i < 100; i += blockDim.x) sw[i] = wt[i];
    if (threadIdx.x < 2) {
        sw[100 + threadIdx.x] = sb[threadIdx.x];
        sw[102 + threadIdx.x] = bias[threadIdx.x];
    }
    __syncthreads();
    int idx = blockIdx.x * blockDim.x + threadIdx.x;
    int total = B_ * H * W;
    if (idx >= total) return;
    int w = idx % W; int t = idx / W; int h = t % H; int b = t / H;
    float nom0 = 0, den0 = 0, nom1 = 0, den1 = 0;
    #pragma unroll
    for (int ci = 0; ci < 2; ++ci) {
        const bf16* xp = xin + (long)(b * 2 + ci) * H * W;
        const bf16* cp = cin + (long)(b * 2 + ci) * H * W;
        #pragma unroll
        for (int dh = 0; dh < 5; ++dh) {
            int ih = h + dh - 2;
            if (ih < 0 || ih >= H) continue;
            #pragma unroll
            for (int dw = 0; dw < 5; ++dw) {
                int iw = w + dw - 2;
                if (iw < 0 || iw >= W) continue;
                float c = b2f(cp[ih * W + iw]);
                float x = b2f(xp[ih * W + iw]);
                float p = x * c;
                float w0 = sw[ci * 25 + dh * 5 + dw];
                float w1 = sw[50 + ci * 25 + dh * 5 + dw];
                nom0 = fmaf(w0, p, nom0); den0 = fmaf(w0, c, den0);
                nom1 = fmaf(w1, p, nom1); den1 = fmaf(w1, c, den1);
            }
        }
    }
    long o0 = (long)(b * 2) * H * W + h * W + w;
    long o1 = o0 + H * W;
    xout[o0] = f2b(nom0 / (den0 + EPSF) + sw[102]);
    xout[o1] = f2b(nom1 / (den1 + EPSF) + sw[103]);
    cout[o0] = f2b(den0 / sw[100]);
    cout[o1] = f2b(den1 / sw[101]);
}

// ---------------------------------------------------------------------------
// 2x2 max-pool on conf (first-max, row-major), gather x at argmax, conf/4.
// ---------------------------------------------------------------------------
__global__ void pool_ds2(const bf16* __restrict__ cin, const bf16* __restrict__ xin,
                         bf16* __restrict__ cout, bf16* __restrict__ xout,
                         int H, int W) {
    int Ho = H / 2, Wo = W / 2;
    int idx = blockIdx.x * blockDim.x + threadIdx.x;
    int total = B_ * 2 * Ho * Wo;
    if (idx >= total) return;
    int wo = idx % Wo; int t = idx / Wo; int ho = t % Ho; int bc = t / Ho;
    const bf16* cp = cin + (long)bc * H * W;
    const bf16* xp = xin + (long)bc * H * W;
    int base = (2 * ho) * W + 2 * wo;
    float c00 = b2f(cp[base]), c01 = b2f(cp[base + 1]);
    float c10 = b2f(cp[base + W]), c11 = b2f(cp[base + W + 1]);
    int sel = 0; float cm = c00;
    if (c01 > cm) { cm = c01; sel = 1; }
    if (c10 > cm) { cm = c10; sel = 2; }
    if (c11 > cm) { cm = c11; sel = 3; }
    bf16 xv = (sel == 0) ? xp[base] : (sel == 1) ? xp[base + 1]
            : (sel == 2) ? xp[base + W] : xp[base + W + 1];
    long o = (long)(bc * Ho + ho) * Wo + wo;
    cout[o] = f2b(cm * 0.25f);
    xout[o] = xv;
}

// ---------------------------------------------------------------------------
// Decoder nconv: 3x3 pad1 over concat of native-level (2ch) and 2x-upsampled
// half-level (2ch). UPF=false: native = weight ch 0-1 (cat(native, up)).
// UPF=true: upsampled = weight ch 0-1 (cat(up, native)) — the final layer.
// FINAL: fuse the trailing 1x1 w7 nconv, write **f32** to d_out.
// ---------------------------------------------------------------------------
template <bool UPF, bool FINAL>
__global__ void nconv_cat(const bf16* __restrict__ nx, const bf16* __restrict__ nc,
                          const bf16* __restrict__ ux, const bf16* __restrict__ uc,
                          const float* __restrict__ wt, const float* __restrict__ sb,
                          const float* __restrict__ bias,
                          const float* __restrict__ w7b, const float* __restrict__ b7,
                          bf16* __restrict__ xout, bf16* __restrict__ cout,
                          float* __restrict__ fxout, float* __restrict__ fcout,
                          int H, int W) {
    __shared__ float sw[80];
    for (int i = threadIdx.x; i < 72; i += blockDim.x) sw[i] = wt[i];
    if (threadIdx.x < 2) {
        sw[72 + threadIdx.x] = sb[threadIdx.x];
        sw[74 + threadIdx.x] = bias[threadIdx.x];
    }
    if (FINAL && threadIdx.x == 0) {
        sw[76] = w7b[0]; sw[77] = w7b[1];   // w7 (in ch 0,1)
        sw[78] = w7b[4];                    // s7 (wb[804] via w7b=wb+800)
        sw[79] = b7[0];
    }
    __syncthreads();
    int idx = blockIdx.x * blockDim.x + threadIdx.x;
    int total = B_ * H * W;
    if (idx >= total) return;
    int Hh = H / 2, Wh = W / 2;
    int w = idx % W; int t = idx / W; int h = t % H; int b = t / H;
    float nom0 = 0, den0 = 0, nom1 = 0, den1 = 0;
    #pragma unroll
    for (int dh = 0; dh < 3; ++dh) {
        int ih = h + dh - 1;
        if (ih < 0 || ih >= H) continue;
        #pragma unroll
        for (int dw = 0; dw < 3; ++dw) {
            int iw = w + dw - 1;
            if (iw < 0 || iw >= W) continue;
            int ih2 = ih >> 1, iw2 = iw >> 1;
            #pragma unroll
            for (int ci = 0; ci < 2; ++ci) {
                int cn = UPF ? (2 + ci) : ci;       // native weight in-ch
                float c = b2f(nc[(long)(b * 2 + ci) * H * W + ih * W + iw]);
                float x = b2f(nx[(long)(b * 2 + ci) * H * W + ih * W + iw]);
                float p = x * c;
                float w0 = sw[cn * 9 + dh * 3 + dw];
                float w1 = sw[36 + cn * 9 + dh * 3 + dw];
                nom0 = fmaf(w0, p, nom0); den0 = fmaf(w0, c, den0);
                nom1 = fmaf(w1, p, nom1); den1 = fmaf(w1, c, den1);
                int cu = UPF ? ci : (2 + ci);       // upsampled weight in-ch
                float c2 = b2f(uc[(long)(b * 2 + ci) * Hh * Wh + ih2 * Wh + iw2]);
                float x2 = b2f(ux[(long)(b * 2 + ci) * Hh * Wh + ih2 * Wh + iw2]);
                float p2 = x2 * c2;
                float v0 = sw[cu * 9 + dh * 3 + dw];
                float v1 = sw[36 + cu * 9 + dh * 3 + dw];
                nom0 = fmaf(v0, p2, nom0); den0 = fmaf(v0, c2, den0);
                nom1 = fmaf(v1, p2, nom1); den1 = fmaf(v1, c2, den1);
            }
        }
    }
    float x0v = nom0 / (den0 + EPSF) + sw[74];
    float x1v = nom1 / (den1 + EPSF) + sw[75];
    float c0v = den0 / sw[72];
    float c1v = den1 / sw[73];
    if (FINAL) {
        float w70 = sw[76], w71 = sw[77];
        float den7 = fmaf(w70, c0v, w71 * c1v);
        float nom7 = fmaf(w70, x0v * c0v, w71 * (x1v * c1v));
        long o = (long)b * H * W + h * W + w;
        fxout[o] = nom7 / (den7 + EPSF) + sw[79];
        fcout[o] = den7 / sw[78];
    } else {
        long o0 = (long)(b * 2) * H * W + h * W + w;
        long o1 = o0 + H * W;
        xout[o0] = f2b(x0v); xout[o1] = f2b(x1v);
        cout[o0] = f2b(c0v); cout[o1] = f2b(c1v);
    }
}

extern "C" void kernel_launch(void* const* d_in, const int* in_sizes, int n_in,
                              void* d_out, int out_size, void* d_ws, size_t ws_size,
                              hipStream_t stream) {
    // Inputs AND outputs are float32 (R7 proved inputs f32; output-f32 explains
    // R5/R6's deterministic 0.639 as bf16-pairs-read-as-f32).
    const float* x0 = (const float*)d_in[0];
    const float* c0 = (const float*)d_in[1];
    const float* w1 = (const float*)d_in[2];
    const float* b1 = (const float*)d_in[3];
    const float* w2 = (const float*)d_in[4];
    const float* b2 = (const float*)d_in[5];
    const float* w3 = (const float*)d_in[6];
    const float* b3 = (const float*)d_in[7];
    const float* w4 = (const float*)d_in[8];
    const float* b4 = (const float*)d_in[9];
    const float* w5 = (const float*)d_in[10];
    const float* b5 = (const float*)d_in[11];
    const float* w6 = (const float*)d_in[12];
    const float* b6 = (const float*)d_in[13];
    const float* w7 = (const float*)d_in[14];
    const float* b7 = (const float*)d_in[15];

    const int N1 = B_ * H1 * W1;            // 6,848,512 (one channel-plane set)
    const int N2 = N1 / 4, N3 = N1 / 16, N4 = N1 / 64;

    // ws: [wb 4KB][Ax 2N1][Ac 2N1][Bc 2N1][Ex 2N2][Ec 2N2] ≈ 96 MB (proven safe)
    float* wb = (float*)d_ws;
    bf16* Ax = (bf16*)((char*)d_ws + 4096);
    bf16* Ac = Ax + 2 * (long)N1;
    bf16* Bc = Ac + 2 * (long)N1;
    bf16* Ex = Bc + 2 * (long)N1;
    bf16* Ec = Ex + 2 * (long)N2;

    // d_out is 2*N1 f32 = 54.8 MB; as bf16 scratch we use only the first
    // 2*N1 bf16 = 27.4 MB. Phased layout (all dead before the final kernel):
    bf16* R = (bf16*)d_out;
    bf16* Bx = R;                   // phase 1: L1 ping-pong x half [0, 2N1)
    bf16* P1x = R;                  // phase 2: x1_ds  [0, 2N2)
    bf16* P1c = R + 2 * (long)N2;   // c1_ds  [2N2, 4N2)
    bf16* T2x = R + 4 * (long)N2;   // L2 temp [4N2, 6N2)
    bf16* T2c = R + 6 * (long)N2;   //         [6N2, 8N2)
    bf16* Dx = P1x;                 // x2,c2 reuse P1 (P1 dead after L2 conv#1)
    bf16* Dc = P1c;
    bf16* C0 = R + 4 * (long)N2;    // carve region (T2 dead after L2 conv#2)
    bf16* P2x = C0;                  bf16* P2c = C0 + 2 * (long)N3;
    bf16* Gx  = C0 + 4 * (long)N3;   bf16* Gc  = C0 + 6 * (long)N3;
    bf16* P3x = C0 + 8 * (long)N3;   bf16* P3c = P3x + 2 * (long)N4;
    bf16* Ix  = P3x + 4 * (long)N4;  bf16* Ic  = Ix + 2 * (long)N4;
    bf16* Fx  = P3x + 8 * (long)N4;  bf16* Fc  = Fx + 2 * (long)N3;

    float* oX = (float*)d_out;
    float* oC = oX + (long)N1;

    prep_weights<<<1, 256, 0, stream>>>(w1, w2, w3, w4, w5, w6, w7, wb);

    const int g1 = (B_ * H1 * W1 + 255) / 256;
    const int g2 = (B_ * H2 * W2 + 255) / 256;
    const int g3 = (B_ * H3 * W3 + 255) / 256;
    const int g4 = (B_ * H4 * W4 + 255) / 256;

    // L1: three 5x5 nconvs (A -> B -> A ping-pong; Bx lives in d_out)
    nconv5_c1f<<<g1, 256, 0, stream>>>(x0, c0, wb, wb + 64, b1, Ax, Ac);
    nconv5_c2<<<g1, 256, 0, stream>>>(Ax, Ac, wb + 96, wb + 224, b2, Bx, Bc, H1, W1);
    nconv5_c2<<<g1, 256, 0, stream>>>(Bx, Bc, wb + 256, wb + 384, b3, Ax, Ac, H1, W1);  // A = x1,c1

    // L1 -> L2 pool (Bx dead; d_out reused for P1/T2/...)
    pool_ds2<<<(B_ * 2 * H2 * W2 + 255) / 256, 256, 0, stream>>>(Ac, Ax, P1c, P1x, H1, W1);
    nconv5_c2<<<g2, 256, 0, stream>>>(P1x, P1c, wb + 96, wb + 224, b2, T2x, T2c, H2, W2);
    nconv5_c2<<<g2, 256, 0, stream>>>(T2x, T2c, wb + 256, wb + 384, b3, Dx, Dc, H2, W2);  // D = x2,c2

    // L3
    pool_ds2<<<(B_ * 2 * H3 * W3 + 255) / 256, 256, 0, stream>>>(Dc, Dx, P2c, P2x, H2, W2);
    nconv5_c2<<<g3, 256, 0, stream>>>(P2x, P2c, wb + 96, wb + 224, b2, Gx, Gc, H3, W3);   // G = x3,c3

    // L4
    pool_ds2<<<(B_ * 2 * H4 * W4 + 255) / 256, 256, 0, stream>>>(Gc, Gx, P3c, P3x, H3, W3);
    nconv5_c2<<<g4, 256, 0, stream>>>(P3x, P3c, wb + 96, wb + 224, b2, Ix, Ic, H4, W4);   // I = x4,c4

    // Decoder (up2 + concat fused into the nconv)
    nconv_cat<false, false><<<g3, 256, 0, stream>>>(Gx, Gc, Ix, Ic, wb + 416, wb + 512, b4,
                                                    nullptr, nullptr, Fx, Fc, nullptr, nullptr, H3, W3);  // F = x34
    nconv_cat<false, false><<<g2, 256, 0, stream>>>(Dx, Dc, Fx, Fc, wb + 544, wb + 640, b5,
                                                    nullptr, nullptr, Ex, Ec, nullptr, nullptr, H2, W2);  // E = x23 (ws)
    // Final: cat(up2(x23), x1) -> w6 3x3 nconv -> fused w7 1x1 -> f32 d_out.
    // Reads only ws (A, E); overwrites the whole d_out.
    nconv_cat<true, true><<<g1, 256, 0, stream>>>(Ax, Ac, Ex, Ec, wb + 672, wb + 768, b6,
                                                  wb + 800, b7, nullptr, nullptr, oX, oC, H1, W1);
}

// Round 9
// 1054.384 us; speedup vs baseline: 1.0149x; 1.0149x over previous
//
#include <hip/hip_runtime.h>
#include <hip/hip_bf16.h>

#define EPSF 1e-20f

typedef __hip_bfloat16 bf16;

__device__ __forceinline__ float b2f(bf16 v) { return __bfloat162float(v); }
__device__ __forceinline__ bf16 f2b(float v) { return __float2bfloat16(v); }

// ---- problem dims (fixed by setup_inputs) ----
#define B_ 16
#define H1 352
#define W1 1216
#define H2 176
#define W2 608
#define H3 88
#define W3 304
#define H4 44
#define W4 152

// ---------------------------------------------------------------------------
// Weight prep (f32 inputs): w = softplus(10*p)/10, plus per-out-ch kernel sums.
// wb layout (floats): wt1@0(50) s1@64(2) | wt2@96(100) s2@224(2) |
// wt3@256(100) s3@384(2) | wt4@416(72) s4@512(2) | wt5@544(72) s5@640(2) |
// wt6@672(72) s6@768(2) | wt7@800(2) s7@804(1).
// ---------------------------------------------------------------------------
__global__ void prep_weights(const float* w1, const float* w2, const float* w3,
                             const float* w4, const float* w5, const float* w6,
                             const float* w7, float* wb) {
    const float* ptrs[7] = {w1, w2, w3, w4, w5, w6, w7};
    const int ns[7]   = {50, 100, 100, 72, 72, 72, 2};
    const int offs[7] = {0, 96, 256, 416, 544, 672, 800};
    for (int it = 0; it < 7; ++it)
        for (int i = threadIdx.x; i < ns[it]; i += blockDim.x) {
            float z = 10.f * ptrs[it][i];
            float sp = (z > 20.f) ? z : log1pf(expf(z));
            wb[offs[it] + i] = sp * 0.1f;
        }
    __syncthreads();
    if (threadIdx.x == 0) {
        const int souts[7] = {2, 2, 2, 2, 2, 2, 1};
        const int klen[7]  = {25, 50, 50, 36, 36, 36, 2};
        const int soff[7]  = {64, 224, 384, 512, 640, 768, 804};
        for (int it = 0; it < 7; ++it)
            for (int o = 0; o < souts[it]; ++o) {
                float s = 0.f;
                for (int i = 0; i < klen[it]; ++i) s += wb[offs[it] + o * klen[it] + i];
                wb[soff[it] + o] = s;
            }
    }
}

// ---------------------------------------------------------------------------
// Fused L1 encoder + pool (validated in R5, identical output to de-fused):
// conv1->conv2->conv3 (5x5 pad2) on x0,c0 (f32); writes x1,c1 (A, bf16 full
// res, needed by the final skip) AND the 2x2-pooled x1_ds,c1_ds (P1, bf16).
// 32x32 fine tile, halo 6. OOB carries x=c=0 == zero-padding semantics.
// LDS: 15488 + 25600 + 20736 + 1048 = 62,872 B.
// ---------------------------------------------------------------------------
#define TDIM 32
__global__ __launch_bounds__(256) void fused_l1pool(
    const float* __restrict__ x0g, const float* __restrict__ c0g,
    const float* __restrict__ wb,
    const float* __restrict__ b1, const float* __restrict__ b2, const float* __restrict__ b3,
    bf16* __restrict__ Axg, bf16* __restrict__ Acg,
    bf16* __restrict__ P1x, bf16* __restrict__ P1c) {

    __shared__ float s0x[44][44], s0c[44][44];
    __shared__ float s1x[2][40][40], s1c[2][40][40];
    __shared__ float s2x[2][36][36], s2c[2][36][36];
    __shared__ float sw[262];
    // sw: w1@0(50), w2@50(100), w3@150(100), s1@250, s2@252, s3@254,
    //     b1@256, b2@258, b3@260
    int tid = threadIdx.x;
    for (int i = tid; i < 262; i += 256) {
        float v;
        if (i < 50)        v = wb[i];
        else if (i < 150)  v = wb[96 + (i - 50)];
        else if (i < 250)  v = wb[256 + (i - 150)];
        else if (i < 252)  v = wb[64 + (i - 250)];
        else if (i < 254)  v = wb[224 + (i - 252)];
        else if (i < 256)  v = wb[384 + (i - 254)];
        else if (i < 258)  v = b1[i - 256];
        else if (i < 260)  v = b2[i - 258];
        else               v = b3[i - 260];
        sw[i] = v;
    }

    const int base_h = blockIdx.y * TDIM;
    const int base_w = blockIdx.x * TDIM;
    const int b = blockIdx.z;
    const float* xp = x0g + (long)b * (H1 * W1);
    const float* cp = c0g + (long)b * (H1 * W1);

    __syncthreads();

    // stage 0: 44x44 input tile (origin -6), zero OOB
    for (int i = tid; i < 44 * 44; i += 256) {
        int r = i / 44, cx = i % 44;
        int gh = base_h - 6 + r, gw = base_w - 6 + cx;
        bool in = (gh >= 0 && gh < H1 && gw >= 0 && gw < W1);
        s0x[r][cx] = in ? xp[gh * W1 + gw] : 0.f;
        s0c[r][cx] = in ? cp[gh * W1 + gw] : 0.f;
    }
    __syncthreads();

    // stage 1: conv1 (CIN=1), 40x40 (origin -4)
    for (int i = tid; i < 40 * 40; i += 256) {
        int r = i / 40, cx = i % 40;
        int gh = base_h - 4 + r, gw = base_w - 4 + cx;
        bool in = (gh >= 0 && gh < H1 && gw >= 0 && gw < W1);
        if (in) {
            float n0 = 0, d0 = 0, n1 = 0, d1 = 0;
            #pragma unroll
            for (int dh = 0; dh < 5; ++dh)
                #pragma unroll
                for (int dw = 0; dw < 5; ++dw) {
                    float c = s0c[r + dh][cx + dw];
                    float p = s0x[r + dh][cx + dw] * c;
                    float w0 = sw[dh * 5 + dw];
                    float w1v = sw[25 + dh * 5 + dw];
                    n0 = fmaf(w0, p, n0); d0 = fmaf(w0, c, d0);
                    n1 = fmaf(w1v, p, n1); d1 = fmaf(w1v, c, d1);
                }
            s1x[0][r][cx] = n0 / (d0 + EPSF) + sw[256];
            s1x[1][r][cx] = n1 / (d1 + EPSF) + sw[257];
            s1c[0][r][cx] = d0 / sw[250];
            s1c[1][r][cx] = d1 / sw[251];
        } else {
            s1x[0][r][cx] = 0.f; s1x[1][r][cx] = 0.f;
            s1c[0][r][cx] = 0.f; s1c[1][r][cx] = 0.f;
        }
    }
    __syncthreads();

    // stage 2: conv2 (CIN=2), 36x36 (origin -2)
    for (int i = tid; i < 36 * 36; i += 256) {
        int r = i / 36, cx = i % 36;
        int gh = base_h - 2 + r, gw = base_w - 2 + cx;
        bool in = (gh >= 0 && gh < H1 && gw >= 0 && gw < W1);
        if (in) {
            float n0 = 0, d0 = 0, n1 = 0, d1 = 0;
            #pragma unroll
            for (int ci = 0; ci < 2; ++ci)
                #pragma unroll
                for (int dh = 0; dh < 5; ++dh)
                    #pragma unroll
                    for (int dw = 0; dw < 5; ++dw) {
                        float c = s1c[ci][r + dh][cx + dw];
                        float p = s1x[ci][r + dh][cx + dw] * c;
                        float w0 = sw[50 + ci * 25 + dh * 5 + dw];
                        float w1v = sw[100 + ci * 25 + dh * 5 + dw];
                        n0 = fmaf(w0, p, n0); d0 = fmaf(w0, c, d0);
                        n1 = fmaf(w1v, p, n1); d1 = fmaf(w1v, c, d1);
                    }
            s2x[0][r][cx] = n0 / (d0 + EPSF) + sw[258];
            s2x[1][r][cx] = n1 / (d1 + EPSF) + sw[259];
            s2c[0][r][cx] = d0 / sw[252];
            s2c[1][r][cx] = d1 / sw[253];
        } else {
            s2x[0][r][cx] = 0.f; s2x[1][r][cx] = 0.f;
            s2c[0][r][cx] = 0.f; s2c[1][r][cx] = 0.f;
        }
    }
    __syncthreads();

    // stage 3: conv3 per 2x2 quad; write full-res A AND pooled P1.
    {
        int pr = tid >> 4, pc = tid & 15;
        float xv[2][4], cv[2][4];
        #pragma unroll
        for (int q = 0; q < 4; ++q) {
            int r = 2 * pr + (q >> 1), cx = 2 * pc + (q & 1);
            float n0 = 0, d0 = 0, n1 = 0, d1 = 0;
            #pragma unroll
            for (int ci = 0; ci < 2; ++ci)
                #pragma unroll
                for (int dh = 0; dh < 5; ++dh)
                    #pragma unroll
                    for (int dw = 0; dw < 5; ++dw) {
                        float c = s2c[ci][r + dh][cx + dw];
                        float p = s2x[ci][r + dh][cx + dw] * c;
                        float w0 = sw[150 + ci * 25 + dh * 5 + dw];
                        float w1v = sw[200 + ci * 25 + dh * 5 + dw];
                        n0 = fmaf(w0, p, n0); d0 = fmaf(w0, c, d0);
                        n1 = fmaf(w1v, p, n1); d1 = fmaf(w1v, c, d1);
                    }
            xv[0][q] = n0 / (d0 + EPSF) + sw[260];
            xv[1][q] = n1 / (d1 + EPSF) + sw[261];
            cv[0][q] = d0 / sw[254];
            cv[1][q] = d1 / sw[255];
        }
        int fh = base_h + 2 * pr, fw = base_w + 2 * pc;
        int ph = (base_h >> 1) + pr, pw = (base_w >> 1) + pc;
        #pragma unroll
        for (int ch = 0; ch < 2; ++ch) {
            // full-res x1,c1 (A)
            #pragma unroll
            for (int q = 0; q < 4; ++q) {
                long o = (long)(b * 2 + ch) * (H1 * W1) + (fh + (q >> 1)) * W1 + (fw + (q & 1));
                Axg[o] = f2b(xv[ch][q]);
                Acg[o] = f2b(cv[ch][q]);
            }
            // pooled (first-max on conf, row-major)
            int sel = 0; float cm = cv[ch][0];
            if (cv[ch][1] > cm) { cm = cv[ch][1]; sel = 1; }
            if (cv[ch][2] > cm) { cm = cv[ch][2]; sel = 2; }
            if (cv[ch][3] > cm) { cm = cv[ch][3]; sel = 3; }
            long o = (long)(b * 2 + ch) * (H2 * W2) + ph * W2 + pw;
            P1c[o] = f2b(cm * 0.25f);
            P1x[o] = f2b(xv[ch][sel]);
        }
    }
}

// ---------------------------------------------------------------------------
// 5x5 pad2 nconv, 2 in ch -> 2 out ch, bf16 I/O, fp32 accumulation.
// ---------------------------------------------------------------------------
__global__ void nconv5_c2(const bf16* __restrict__ xin, const bf16* __restrict__ cin,
                          const float* __restrict__ wt, const float* __restrict__ sb,
                          const float* __restrict__ bias,
                          bf16* __restrict__ xout, bf16* __restrict__ cout,
                          int H, int W) {
    __shared__ float sw[104];
    for (int i = threadIdx.x; i < 100; i += blockDim.x) sw[i] = wt[i];
    if (threadIdx.x < 2) {
        sw[100 + threadIdx.x] = sb[threadIdx.x];
        sw[102 + threadIdx.x] = bias[threadIdx.x];
    }
    __syncthreads();
    int idx = blockIdx.x * blockDim.x + threadIdx.x;
    int total = B_ * H * W;
    if (idx >= total) return;
    int w = idx % W; int t = idx / W; int h = t % H; int b = t / H;
    float nom0 = 0, den0 = 0, nom1 = 0, den1 = 0;
    #pragma unroll
    for (int ci = 0; ci < 2; ++ci) {
        const bf16* xp = xin + (long)(b * 2 + ci) * H * W;
        const bf16* cp = cin + (long)(b * 2 + ci) * H * W;
        #pragma unroll
        for (int dh = 0; dh < 5; ++dh) {
            int ih = h + dh - 2;
            if (ih < 0 || ih >= H) continue;
            #pragma unroll
            for (int dw = 0; dw < 5; ++dw) {
                int iw = w + dw - 2;
                if (iw < 0 || iw >= W) continue;
                float c = b2f(cp[ih * W + iw]);
                float x = b2f(xp[ih * W + iw]);
                float p = x * c;
                float w0 = sw[ci * 25 + dh * 5 + dw];
                float w1 = sw[50 + ci * 25 + dh * 5 + dw];
                nom0 = fmaf(w0, p, nom0); den0 = fmaf(w0, c, den0);
                nom1 = fmaf(w1, p, nom1); den1 = fmaf(w1, c, den1);
            }
        }
    }
    long o0 = (long)(b * 2) * H * W + h * W + w;
    long o1 = o0 + H * W;
    xout[o0] = f2b(nom0 / (den0 + EPSF) + sw[102]);
    xout[o1] = f2b(nom1 / (den1 + EPSF) + sw[103]);
    cout[o0] = f2b(den0 / sw[100]);
    cout[o1] = f2b(den1 / sw[101]);
}

// ---------------------------------------------------------------------------
// 2x2 max-pool on conf (first-max, row-major), gather x at argmax, conf/4.
// ---------------------------------------------------------------------------
__global__ void pool_ds2(const bf16* __restrict__ cin, const bf16* __restrict__ xin,
                         bf16* __restrict__ cout, bf16* __restrict__ xout,
                         int H, int W) {
    int Ho = H / 2, Wo = W / 2;
    int idx = blockIdx.x * blockDim.x + threadIdx.x;
    int total = B_ * 2 * Ho * Wo;
    if (idx >= total) return;
    int wo = idx % Wo; int t = idx / Wo; int ho = t % Ho; int bc = t / Ho;
    const bf16* cp = cin + (long)bc * H * W;
    const bf16* xp = xin + (long)bc * H * W;
    int base = (2 * ho) * W + 2 * wo;
    float c00 = b2f(cp[base]), c01 = b2f(cp[base + 1]);
    float c10 = b2f(cp[base + W]), c11 = b2f(cp[base + W + 1]);
    int sel = 0; float cm = c00;
    if (c01 > cm) { cm = c01; sel = 1; }
    if (c10 > cm) { cm = c10; sel = 2; }
    if (c11 > cm) { cm = c11; sel = 3; }
    bf16 xv = (sel == 0) ? xp[base] : (sel == 1) ? xp[base + 1]
            : (sel == 2) ? xp[base + W] : xp[base + W + 1];
    long o = (long)(bc * Ho + ho) * Wo + wo;
    cout[o] = f2b(cm * 0.25f);
    xout[o] = xv;
}

// ---------------------------------------------------------------------------
// Decoder nconv (mid-levels): 3x3 pad1 over concat(native [wch 0-1],
// up2(half) [wch 2-3]). bf16 I/O.
// ---------------------------------------------------------------------------
__global__ void nconv_cat(const bf16* __restrict__ nx, const bf16* __restrict__ nc,
                          const bf16* __restrict__ ux, const bf16* __restrict__ uc,
                          const float* __restrict__ wt, const float* __restrict__ sb,
                          const float* __restrict__ bias,
                          bf16* __restrict__ xout, bf16* __restrict__ cout,
                          int H, int W) {
    __shared__ float sw[76];
    for (int i = threadIdx.x; i < 72; i += blockDim.x) sw[i] = wt[i];
    if (threadIdx.x < 2) {
        sw[72 + threadIdx.x] = sb[threadIdx.x];
        sw[74 + threadIdx.x] = bias[threadIdx.x];
    }
    __syncthreads();
    int idx = blockIdx.x * blockDim.x + threadIdx.x;
    int total = B_ * H * W;
    if (idx >= total) return;
    int Hh = H / 2, Wh = W / 2;
    int w = idx % W; int t = idx / W; int h = t % H; int b = t / H;
    float nom0 = 0, den0 = 0, nom1 = 0, den1 = 0;
    #pragma unroll
    for (int dh = 0; dh < 3; ++dh) {
        int ih = h + dh - 1;
        if (ih < 0 || ih >= H) continue;
        #pragma unroll
        for (int dw = 0; dw < 3; ++dw) {
            int iw = w + dw - 1;
            if (iw < 0 || iw >= W) continue;
            int ih2 = ih >> 1, iw2 = iw >> 1;
            #pragma unroll
            for (int ci = 0; ci < 2; ++ci) {
                float c = b2f(nc[(long)(b * 2 + ci) * H * W + ih * W + iw]);
                float x = b2f(nx[(long)(b * 2 + ci) * H * W + ih * W + iw]);
                float p = x * c;
                float w0 = sw[ci * 9 + dh * 3 + dw];
                float w1 = sw[36 + ci * 9 + dh * 3 + dw];
                nom0 = fmaf(w0, p, nom0); den0 = fmaf(w0, c, den0);
                nom1 = fmaf(w1, p, nom1); den1 = fmaf(w1, c, den1);
                float c2 = b2f(uc[(long)(b * 2 + ci) * Hh * Wh + ih2 * Wh + iw2]);
                float x2 = b2f(ux[(long)(b * 2 + ci) * Hh * Wh + ih2 * Wh + iw2]);
                float p2 = x2 * c2;
                float v0 = sw[(2 + ci) * 9 + dh * 3 + dw];
                float v1 = sw[36 + (2 + ci) * 9 + dh * 3 + dw];
                nom0 = fmaf(v0, p2, nom0); den0 = fmaf(v0, c2, den0);
                nom1 = fmaf(v1, p2, nom1); den1 = fmaf(v1, c2, den1);
            }
        }
    }
    long o0 = (long)(b * 2) * H * W + h * W + w;
    long o1 = o0 + H * W;
    xout[o0] = f2b(nom0 / (den0 + EPSF) + sw[74]);
    xout[o1] = f2b(nom1 / (den1 + EPSF) + sw[75]);
    cout[o0] = f2b(den0 / sw[72]);
    cout[o1] = f2b(den1 / sw[73]);
}

// ---------------------------------------------------------------------------
// Final tiled kernel: cat(up2(x23) [wch 0-1], x1 [wch 2-3]) -> w6 3x3 nconv
// -> fused w7 1x1 nconv -> f32 d_out. 32x32 tile; A halo 1, E half-res tile
// 18x18. LDS ≈ 24 KB.
// ---------------------------------------------------------------------------
__global__ __launch_bounds__(256) void final_tiled(
    const bf16* __restrict__ Axg, const bf16* __restrict__ Acg,
    const bf16* __restrict__ Exg, const bf16* __restrict__ Ecg,
    const float* __restrict__ wb,
    const float* __restrict__ b6g, const float* __restrict__ b7g,
    float* __restrict__ oX, float* __restrict__ oC) {

    __shared__ float aX[2][34][34], aC[2][34][34];
    __shared__ float eX[2][18][18], eC[2][18][18];
    __shared__ float sw[80];
    // sw: w6@0(72) s6@72(2) b6@74(2) w7@76(2) s7@78 b7@79
    int tid = threadIdx.x;
    for (int i = tid; i < 80; i += 256) {
        float v;
        if (i < 72)       v = wb[672 + i];
        else if (i < 74)  v = wb[768 + (i - 72)];
        else if (i < 76)  v = b6g[i - 74];
        else if (i < 78)  v = wb[800 + (i - 76)];
        else if (i == 78) v = wb[804];
        else              v = b7g[0];
        sw[i] = v;
    }

    const int bh = blockIdx.y * 32, bw = blockIdx.x * 32, b = blockIdx.z;
    const int eh0 = (bh - 1) >> 1, ew0 = (bw - 1) >> 1;   // arithmetic shift: floor

    // A tile 34x34 (origin -1), zero OOB
    for (int i = tid; i < 34 * 34; i += 256) {
        int r = i / 34, c = i % 34;
        int gh = bh - 1 + r, gw = bw - 1 + c;
        bool in = (gh >= 0 && gh < H1 && gw >= 0 && gw < W1);
        #pragma unroll
        for (int ch = 0; ch < 2; ++ch) {
            long o = (long)(b * 2 + ch) * (H1 * W1) + gh * W1 + gw;
            aX[ch][r][c] = in ? b2f(Axg[o]) : 0.f;
            aC[ch][r][c] = in ? b2f(Acg[o]) : 0.f;
        }
    }
    // E tile 18x18 (origin eh0, ew0), zero OOB
    for (int i = tid; i < 18 * 18; i += 256) {
        int r = i / 18, c = i % 18;
        int gh = eh0 + r, gw = ew0 + c;
        bool in = (gh >= 0 && gh < H2 && gw >= 0 && gw < W2);
        #pragma unroll
        for (int ch = 0; ch < 2; ++ch) {
            long o = (long)(b * 2 + ch) * (H2 * W2) + gh * W2 + gw;
            eX[ch][r][c] = in ? b2f(Exg[o]) : 0.f;
            eC[ch][r][c] = in ? b2f(Ecg[o]) : 0.f;
        }
    }
    __syncthreads();

    for (int i = tid; i < 32 * 32; i += 256) {
        int r = i >> 5, c = i & 31;
        int gh = bh + r, gw = bw + c;
        float n0 = 0, d0 = 0, n1 = 0, d1 = 0;
        #pragma unroll
        for (int dh = 0; dh < 3; ++dh) {
            int ih = gh - 1 + dh;
            if (ih < 0 || ih >= H1) continue;
            int lr = r + dh, le = (ih >> 1) - eh0;
            #pragma unroll
            for (int dw = 0; dw < 3; ++dw) {
                int iw = gw - 1 + dw;
                if (iw < 0 || iw >= W1) continue;
                int lc = c + dw, lw = (iw >> 1) - ew0;
                #pragma unroll
                for (int ci = 0; ci < 2; ++ci) {
                    float cE = eC[ci][le][lw];
                    float pE = eX[ci][le][lw] * cE;
                    float u0 = sw[ci * 9 + dh * 3 + dw];
                    float u1 = sw[36 + ci * 9 + dh * 3 + dw];
                    n0 = fmaf(u0, pE, n0); d0 = fmaf(u0, cE, d0);
                    n1 = fmaf(u1, pE, n1); d1 = fmaf(u1, cE, d1);
                    float cN = aC[ci][lr][lc];
                    float pN = aX[ci][lr][lc] * cN;
                    float v0 = sw[(2 + ci) * 9 + dh * 3 + dw];
                    float v1 = sw[36 + (2 + ci) * 9 + dh * 3 + dw];
                    n0 = fmaf(v0, pN, n0); d0 = fmaf(v0, cN, d0);
                    n1 = fmaf(v1, pN, n1); d1 = fmaf(v1, cN, d1);
                }
            }
        }
        float x0v = n0 / (d0 + EPSF) + sw[74];
        float x1v = n1 / (d1 + EPSF) + sw[75];
        float c0v = d0 / sw[72];
        float c1v = d1 / sw[73];
        float w70 = sw[76], w71 = sw[77];
        float den7 = fmaf(w70, c0v, w71 * c1v);
        float nom7 = fmaf(w70, x0v * c0v, w71 * (x1v * c1v));
        long o = (long)b * (H1 * W1) + gh * W1 + gw;
        oX[o] = nom7 / (den7 + EPSF) + sw[79];
        oC[o] = den7 / sw[78];
    }
}

extern "C" void kernel_launch(void* const* d_in, const int* in_sizes, int n_in,
                              void* d_out, int out_size, void* d_ws, size_t ws_size,
                              hipStream_t stream) {
    const float* x0 = (const float*)d_in[0];
    const float* c0 = (const float*)d_in[1];
    const float* w1 = (const float*)d_in[2];
    const float* b1 = (const float*)d_in[3];
    const float* w2 = (const float*)d_in[4];
    const float* b2 = (const float*)d_in[5];
    const float* w3 = (const float*)d_in[6];
    const float* b3 = (const float*)d_in[7];
    const float* w4 = (const float*)d_in[8];
    const float* b4 = (const float*)d_in[9];
    const float* w5 = (const float*)d_in[10];
    const float* b5 = (const float*)d_in[11];
    const float* w6 = (const float*)d_in[12];
    const float* b6 = (const float*)d_in[13];
    const float* w7 = (const float*)d_in[14];
    const float* b7 = (const float*)d_in[15];

    const int N1 = B_ * H1 * W1;            // 6,848,512
    const int N2 = N1 / 4, N3 = N1 / 16, N4 = N1 / 64;

    // ws: [wb 4KB][Ax 2N1][Ac 2N1][Ex 2N2][Ec 2N2] ≈ 69 MB (under proven 96 MB)
    float* wb = (float*)d_ws;
    bf16* Ax = (bf16*)((char*)d_ws + 4096);
    bf16* Ac = Ax + 2 * (long)N1;
    bf16* Ex = Ac + 2 * (long)N1;
    bf16* Ec = Ex + 2 * (long)N2;

    // d_out (2N1 f32) as bf16 scratch (uses first 27.4 of 54.8 MB):
    bf16* R = (bf16*)d_out;
    bf16* P1x = R;                  // x1_ds  [0, 2N2)
    bf16* P1c = R + 2 * (long)N2;   // c1_ds  [2N2, 4N2)
    bf16* T2x = R + 4 * (long)N2;   // L2 temp [4N2, 6N2)
    bf16* T2c = R + 6 * (long)N2;   //         [6N2, 8N2)
    bf16* Dx = P1x;                 // x2,c2 reuse P1 (dead after L2 conv#1)
    bf16* Dc = P1c;
    bf16* C0 = R + 4 * (long)N2;    // carve region (T2 dead after L2 conv#2)
    bf16* P2x = C0;                  bf16* P2c = C0 + 2 * (long)N3;
    bf16* Gx  = C0 + 4 * (long)N3;   bf16* Gc  = C0 + 6 * (long)N3;
    bf16* P3x = C0 + 8 * (long)N3;   bf16* P3c = P3x + 2 * (long)N4;
    bf16* Ix  = P3x + 4 * (long)N4;  bf16* Ic  = Ix + 2 * (long)N4;
    bf16* Fx  = P3x + 8 * (long)N4;  bf16* Fc  = Fx + 2 * (long)N3;
    // Fc ends at C0 + 14*N3 <= end of the 2N1-bf16 region. OK.

    float* oX = (float*)d_out;
    float* oC = oX + (long)N1;

    prep_weights<<<1, 256, 0, stream>>>(w1, w2, w3, w4, w5, w6, w7, wb);

    // Fused L1 encoder + pool: x0,c0 -> A (ws) + P1 (d_out)
    dim3 gridF(W1 / TDIM, H1 / TDIM, B_);   // 38 x 11 x 16
    fused_l1pool<<<gridF, 256, 0, stream>>>(x0, c0, wb, b1, b2, b3, Ax, Ac, P1x, P1c);

    const int g2 = (B_ * H2 * W2 + 255) / 256;
    const int g3 = (B_ * H3 * W3 + 255) / 256;
    const int g4 = (B_ * H4 * W4 + 255) / 256;

    // L2
    nconv5_c2<<<g2, 256, 0, stream>>>(P1x, P1c, wb + 96, wb + 224, b2, T2x, T2c, H2, W2);
    nconv5_c2<<<g2, 256, 0, stream>>>(T2x, T2c, wb + 256, wb + 384, b3, Dx, Dc, H2, W2);  // D = x2,c2

    // L3
    pool_ds2<<<(B_ * 2 * H3 * W3 + 255) / 256, 256, 0, stream>>>(Dc, Dx, P2c, P2x, H2, W2);
    nconv5_c2<<<g3, 256, 0, stream>>>(P2x, P2c, wb + 96, wb + 224, b2, Gx, Gc, H3, W3);   // G = x3,c3

    // L4
    pool_ds2<<<(B_ * 2 * H4 * W4 + 255) / 256, 256, 0, stream>>>(Gc, Gx, P3c, P3x, H3, W3);
    nconv5_c2<<<g4, 256, 0, stream>>>(P3x, P3c, wb + 96, wb + 224, b2, Ix, Ic, H4, W4);   // I = x4,c4

    // Decoder
    nconv_cat<<<g3, 256, 0, stream>>>(Gx, Gc, Ix, Ic, wb + 416, wb + 512, b4, Fx, Fc, H3, W3);  // F = x34
    nconv_cat<<<g2, 256, 0, stream>>>(Dx, Dc, Fx, Fc, wb + 544, wb + 640, b5, Ex, Ec, H2, W2);  // E = x23 (ws)

    // Final: tiled w6+w7 -> f32 d_out (reads only ws; rewrites all of d_out)
    dim3 gridL(W1 / 32, H1 / 32, B_);       // 38 x 11 x 16
    final_tiled<<<gridL, 256, 0, stream>>>(Ax, Ac, Ex, Ec, wb, b6, b7, oX, oC);
}